// Round 4
// baseline (1099.007 us; speedup 1.0000x reference)
//
#include <hip/hip_runtime.h>

#define F_IN 500
#define HDIM 64
#define CDIM 10

// ---------------------------------------------------------------------------
// bf16 helpers (round-to-nearest-even pack, cheap unpack)
// ---------------------------------------------------------------------------
__device__ inline unsigned short f2bf(float f) {
    unsigned int u = __float_as_uint(f);
    u += 0x7fffu + ((u >> 16) & 1u);
    return (unsigned short)(u >> 16);
}

// ---------------------------------------------------------------------------
// Stage 1: in-degree histogram (real edges only; self-loop = +1 at rsqrt)
// ---------------------------------------------------------------------------
__global__ void deg_count_kernel(const int* __restrict__ dst, int E,
                                 int* __restrict__ deg) {
    int e = blockIdx.x * blockDim.x + threadIdx.x;
    if (e < E) atomicAdd(&deg[dst[e]], 1);
}

__global__ void dis_kernel(const int* __restrict__ deg, float* __restrict__ dis,
                           int N) {
    int i = blockIdx.x * blockDim.x + threadIdx.x;
    if (i < N) dis[i] = rsqrtf((float)(deg[i] + 1));
}

// ---------------------------------------------------------------------------
// Stage 2: hierarchical exclusive scan deg -> row_ptr[N+1]
// ---------------------------------------------------------------------------
__global__ void scan_block_kernel(const int* __restrict__ deg,
                                  int* __restrict__ row_ptr,
                                  int* __restrict__ blk_sum, int Np1) {
    __shared__ int wsum[16];
    int i = blockIdx.x * 1024 + threadIdx.x;
    int v = (i < Np1 - 1) ? deg[i] : 0;
    int lane = threadIdx.x & 63;
    int wid = threadIdx.x >> 6;
    int x = v;
#pragma unroll
    for (int off = 1; off < 64; off <<= 1) {
        int y = __shfl_up(x, off);
        if (lane >= off) x += y;
    }
    if (lane == 63) wsum[wid] = x;
    __syncthreads();
    if (threadIdx.x < 16) {
        int ws = wsum[threadIdx.x];
#pragma unroll
        for (int off = 1; off < 16; off <<= 1) {
            int y = __shfl_up(ws, off);
            if ((int)threadIdx.x >= off) ws += y;
        }
        wsum[threadIdx.x] = ws;
    }
    __syncthreads();
    int wp = (wid > 0) ? wsum[wid - 1] : 0;
    if (i < Np1) row_ptr[i] = wp + x - v;
    if (threadIdx.x == 1023) blk_sum[blockIdx.x] = wp + x;
}

__global__ void scan_top_kernel(int* __restrict__ blk_sum, int nb) {
    int carry = 0;
    for (int base = 0; base < nb; base += 64) {
        int i = base + (int)threadIdx.x;
        int v = (i < nb) ? blk_sum[i] : 0;
        int x = v;
#pragma unroll
        for (int off = 1; off < 64; off <<= 1) {
            int y = __shfl_up(x, off);
            if ((int)threadIdx.x >= off) x += y;
        }
        if (i < nb) blk_sum[i] = carry + x - v;
        carry += __shfl(x, 63);
    }
}

__global__ void scan_add_kernel(int* __restrict__ row_ptr,
                                const int* __restrict__ blk_sum, int Np1) {
    int i = blockIdx.x * blockDim.x + threadIdx.x;
    if (i < Np1) row_ptr[i] += blk_sum[i >> 10];
}

// ---------------------------------------------------------------------------
// Stage 3: CSR fill
// ---------------------------------------------------------------------------
__global__ void csr_fill_kernel(const int* __restrict__ src,
                                const int* __restrict__ dst,
                                const int* __restrict__ row_ptr,
                                int* __restrict__ cursor,
                                int* __restrict__ csr_src, int E) {
    int e = blockIdx.x * blockDim.x + threadIdx.x;
    if (e >= E) return;
    int d = dst[e];
    int pos = atomicAdd(&cursor[d], 1);
    csr_src[row_ptr[d] + pos] = src[e];
}

// ---------------------------------------------------------------------------
// Stage 4: h1 = x @ W1 — W1^T fully resident in LDS (125 KB, gfx950 has 160).
// 256 persistent blocks x 1024 threads.  lane = feature; wave owns 8 nodes
// per chunk.  Inner loop: 1 ds_read_b128 (W) + 8 scalar s_load_dwordx4 (x,
// node index forced wave-uniform via readfirstlane) + 32 FMA.  No syncthreads
// in the hot loop; output stored as bf16 for the gather stage.
// ---------------------------------------------------------------------------
__global__ __launch_bounds__(1024, 4) void gemm1_kernel(
        const float* __restrict__ x, const float* __restrict__ W1,
        unsigned short* __restrict__ h1b, int N) {
    __shared__ float Wt[HDIM * F_IN];  // [f][k], 128000 B
    const int t = threadIdx.x;
    for (int idx = t; idx < F_IN * HDIM; idx += 1024) {
        int k = idx >> 6, f = idx & 63;
        Wt[f * F_IN + k] = W1[idx];
    }
    __syncthreads();

    const int lane = t & 63;
    const int wid = t >> 6;
    const int gw = blockIdx.x * 16 + wid;
    const int nwaves = gridDim.x * 16;
    const int ngroups = (N + 7) / 8;
    const float* wrow = Wt + lane * F_IN;

    for (int g = gw; g < ngroups; g += nwaves) {
        int n0 = g * 8;
        size_t xb[8];
#pragma unroll
        for (int i = 0; i < 8; ++i) {
            int n = n0 + i;
            if (n >= N) n = N - 1;                       // clamp (no OOB)
            xb[i] = (size_t)__builtin_amdgcn_readfirstlane(n) * F_IN;
        }
        float acc[8];
#pragma unroll
        for (int i = 0; i < 8; ++i) acc[i] = 0.f;

        for (int k = 0; k < F_IN; k += 4) {
            float4 wv = *reinterpret_cast<const float4*>(wrow + k);
#pragma unroll
            for (int i = 0; i < 8; ++i) {
                float4 xv = *reinterpret_cast<const float4*>(x + xb[i] + k);
                acc[i] = fmaf(xv.x, wv.x, acc[i]);
                acc[i] = fmaf(xv.y, wv.y, acc[i]);
                acc[i] = fmaf(xv.z, wv.z, acc[i]);
                acc[i] = fmaf(xv.w, wv.w, acc[i]);
            }
        }
#pragma unroll
        for (int i = 0; i < 8; ++i) {
            int n = n0 + i;
            if (n < N) h1b[(size_t)n * HDIM + lane] = f2bf(acc[i]);
        }
    }
}

// ---------------------------------------------------------------------------
// Stage 5: gather layer 1 (bf16 h1).  One wave per node; half-wave per edge
// parity; lane&31 = feature pair.  128 B coalesced row reads, fp32 acc,
// shfl_xor(32) to combine halves.
// ---------------------------------------------------------------------------
__global__ void gather1_kernel(const int* __restrict__ row_ptr,
                               const int* __restrict__ csr_src,
                               const float* __restrict__ dis,
                               const unsigned short* __restrict__ h1b,
                               float* __restrict__ agg1, int N) {
    int nid = blockIdx.x * 4 + (threadIdx.x >> 6);
    if (nid >= N) return;
    int node = __builtin_amdgcn_readfirstlane(nid);
    int lane = threadIdx.x & 63;
    int half = lane >> 5;
    int c = lane & 31;  // features 2c, 2c+1
    int beg = row_ptr[node];
    int end = row_ptr[node + 1];
    float dd = dis[node];
    float a0 = 0.f, a1 = 0.f;
    if (half == 0) {  // self-loop
        unsigned int w = *reinterpret_cast<const unsigned int*>(
            h1b + (size_t)node * HDIM + 2 * c);
        float dd2 = dd * dd;
        a0 = __uint_as_float(w << 16) * dd2;
        a1 = __uint_as_float(w & 0xffff0000u) * dd2;
    }
    int p = beg + half;
    for (; p + 2 < end; p += 4) {  // 2 edges in flight per half
        int s0 = csr_src[p];
        int s1 = csr_src[p + 2];
        float nm0 = dis[s0] * dd;
        float nm1 = dis[s1] * dd;
        unsigned int w0 = *reinterpret_cast<const unsigned int*>(
            h1b + (size_t)s0 * HDIM + 2 * c);
        unsigned int w1 = *reinterpret_cast<const unsigned int*>(
            h1b + (size_t)s1 * HDIM + 2 * c);
        a0 = fmaf(__uint_as_float(w0 << 16), nm0, a0);
        a1 = fmaf(__uint_as_float(w0 & 0xffff0000u), nm0, a1);
        a0 = fmaf(__uint_as_float(w1 << 16), nm1, a0);
        a1 = fmaf(__uint_as_float(w1 & 0xffff0000u), nm1, a1);
    }
    if (p < end) {
        int s0 = csr_src[p];
        float nm0 = dis[s0] * dd;
        unsigned int w0 = *reinterpret_cast<const unsigned int*>(
            h1b + (size_t)s0 * HDIM + 2 * c);
        a0 = fmaf(__uint_as_float(w0 << 16), nm0, a0);
        a1 = fmaf(__uint_as_float(w0 & 0xffff0000u), nm0, a1);
    }
    a0 += __shfl_xor(a0, 32);
    a1 += __shfl_xor(a1, 32);
    if (half == 0) {
        *reinterpret_cast<float2*>(agg1 + (size_t)node * HDIM + 2 * c) =
            make_float2(a0, a1);
    }
}

// ---------------------------------------------------------------------------
// Stage 6: layer 2 dense: t = relu(agg1 + b1); h2 = t @ W2
// ---------------------------------------------------------------------------
__global__ void layer2_kernel(const float* __restrict__ agg1,
                              const float* __restrict__ b1,
                              const float* __restrict__ W2,
                              float* __restrict__ h2, int N) {
    int n = blockIdx.x * blockDim.x + threadIdx.x;
    if (n >= N) return;
    const float* ar = agg1 + (size_t)n * HDIM;
    float t[HDIM];
#pragma unroll
    for (int c = 0; c < HDIM; ++c) {
        float v = ar[c] + b1[c];
        t[c] = v > 0.f ? v : 0.f;
    }
    float* h2r = h2 + (size_t)n * CDIM;
#pragma unroll
    for (int j = 0; j < CDIM; ++j) {
        float acc = 0.f;
#pragma unroll
        for (int c = 0; c < HDIM; ++c) acc = fmaf(t[c], W2[c * CDIM + j], acc);
        h2r[j] = acc;
    }
}

// ---------------------------------------------------------------------------
// Stage 7: gather layer 2.  16 lanes per node (10 active), j = feature.
// ---------------------------------------------------------------------------
__global__ void gather2_kernel(const int* __restrict__ row_ptr,
                               const int* __restrict__ csr_src,
                               const float* __restrict__ dis,
                               const float* __restrict__ h2,
                               const float* __restrict__ b2,
                               float* __restrict__ out, int N) {
    int t = blockIdx.x * blockDim.x + threadIdx.x;
    int node = t >> 4;
    int j = t & 15;
    if (node >= N || j >= CDIM) return;
    int beg = row_ptr[node];
    int end = row_ptr[node + 1];
    float dd = dis[node];
    float acc = h2[(size_t)node * CDIM + j] * dd * dd + b2[j];
    for (int p = beg; p < end; ++p) {
        int s = csr_src[p];
        acc = fmaf(h2[(size_t)s * CDIM + j], dis[s] * dd, acc);
    }
    out[(size_t)node * CDIM + j] = acc;
}

// ---------------------------------------------------------------------------
extern "C" void kernel_launch(void* const* d_in, const int* in_sizes, int n_in,
                              void* d_out, int out_size, void* d_ws,
                              size_t ws_size, hipStream_t stream) {
    const float* x  = (const float*)d_in[0];
    const int*   ei = (const int*)d_in[1];
    const float* W1 = (const float*)d_in[2];
    const float* b1 = (const float*)d_in[3];
    const float* W2 = (const float*)d_in[4];
    const float* b2 = (const float*)d_in[5];

    const int N = in_sizes[0] / F_IN;   // 100000
    const int E = in_sizes[1] / 2;      // 1600000
    const int* src = ei;
    const int* dst = ei + E;
    float* out = (float*)d_out;

    const int Np1 = N + 1;
    const int nscan_blocks = (Np1 + 1023) / 1024;

    // workspace layout (~46 MB)
    char* w = (char*)d_ws;
    int*            deg     = (int*)w;            w += (size_t)N * 4;  // zeroed
    int*            cursor  = (int*)w;            w += (size_t)N * 4;  // zeroed
    float*          dis     = (float*)w;          w += (size_t)N * 4;
    int*            row_ptr = (int*)w;            w += (size_t)(N + 4) * 4;
    int*            blk_sum = (int*)w;            w += (size_t)((nscan_blocks + 63) & ~63) * 4;
    int*            csr_src = (int*)w;            w += (size_t)E * 4;
    unsigned short* h1b     = (unsigned short*)w; w += (size_t)N * HDIM * 2;
    float*          agg1    = (float*)w;          w += (size_t)N * HDIM * 4;
    float*          h2      = (float*)h1b;  // h1b dead after gather1; reuse

    hipMemsetAsync(deg, 0, (size_t)N * 2 * 4, stream);  // deg + cursor

    deg_count_kernel<<<(E + 255) / 256, 256, 0, stream>>>(dst, E, deg);
    dis_kernel<<<(N + 255) / 256, 256, 0, stream>>>(deg, dis, N);
    scan_block_kernel<<<nscan_blocks, 1024, 0, stream>>>(deg, row_ptr, blk_sum,
                                                         Np1);
    scan_top_kernel<<<1, 64, 0, stream>>>(blk_sum, nscan_blocks);
    scan_add_kernel<<<(Np1 + 255) / 256, 256, 0, stream>>>(row_ptr, blk_sum,
                                                           Np1);
    csr_fill_kernel<<<(E + 255) / 256, 256, 0, stream>>>(src, dst, row_ptr,
                                                         cursor, csr_src, E);
    gemm1_kernel<<<256, 1024, 0, stream>>>(x, W1, h1b, N);
    gather1_kernel<<<(N + 3) / 4, 256, 0, stream>>>(row_ptr, csr_src, dis, h1b,
                                                    agg1, N);
    layer2_kernel<<<(N + 255) / 256, 256, 0, stream>>>(agg1, b1, W2, h2, N);
    {
        long long nthreads = (long long)N * 16;
        int blocks = (int)((nthreads + 255) / 256);
        gather2_kernel<<<blocks, 256, 0, stream>>>(row_ptr, csr_src, dis, h2,
                                                   b2, out, N);
    }
}

// Round 5
// 587.381 us; speedup vs baseline: 1.8710x; 1.8710x over previous
//
#include <hip/hip_runtime.h>

#define F_IN 500
#define HDIM 64
#define CDIM 10
#define KPAD 512           // K padded to 16 MFMA stages of 32
#define NSTAGE 16

typedef __attribute__((ext_vector_type(8))) short bf16x8;
typedef __attribute__((ext_vector_type(4))) float floatx4;

// RNE fp32 -> bf16 bits
__device__ inline unsigned short f2bf(float f) {
    unsigned int u = __float_as_uint(f);
    u += 0x7fffu + ((u >> 16) & 1u);
    return (unsigned short)(u >> 16);
}

// ---------------------------------------------------------------------------
// Stage 1: in-degree histogram (self-loop handled as +1 in rsqrt)
// ---------------------------------------------------------------------------
__global__ void deg_count_kernel(const int* __restrict__ dst, int E,
                                 int* __restrict__ deg) {
    int e = blockIdx.x * blockDim.x + threadIdx.x;
    if (e < E) atomicAdd(&deg[dst[e]], 1);
}

// ---------------------------------------------------------------------------
// Stage 2: hierarchical exclusive scan deg -> row_ptr[N+1]; dis fused here.
// ---------------------------------------------------------------------------
__global__ void scan_block_kernel(const int* __restrict__ deg,
                                  int* __restrict__ row_ptr,
                                  int* __restrict__ blk_sum,
                                  float* __restrict__ dis, int Np1) {
    __shared__ int wsum[16];
    int i = blockIdx.x * 1024 + threadIdx.x;
    int v = (i < Np1 - 1) ? deg[i] : 0;
    if (i < Np1 - 1) dis[i] = rsqrtf((float)(v + 1));
    int lane = threadIdx.x & 63;
    int wid = threadIdx.x >> 6;
    int x = v;
#pragma unroll
    for (int off = 1; off < 64; off <<= 1) {
        int y = __shfl_up(x, off);
        if (lane >= off) x += y;
    }
    if (lane == 63) wsum[wid] = x;
    __syncthreads();
    if (threadIdx.x < 16) {
        int ws = wsum[threadIdx.x];
#pragma unroll
        for (int off = 1; off < 16; off <<= 1) {
            int y = __shfl_up(ws, off);
            if ((int)threadIdx.x >= off) ws += y;
        }
        wsum[threadIdx.x] = ws;
    }
    __syncthreads();
    int wp = (wid > 0) ? wsum[wid - 1] : 0;
    if (i < Np1) row_ptr[i] = wp + x - v;
    if (threadIdx.x == 1023) blk_sum[blockIdx.x] = wp + x;
}

__global__ void scan_top_kernel(int* __restrict__ blk_sum, int nb) {
    int carry = 0;
    for (int base = 0; base < nb; base += 64) {
        int i = base + (int)threadIdx.x;
        int v = (i < nb) ? blk_sum[i] : 0;
        int x = v;
#pragma unroll
        for (int off = 1; off < 64; off <<= 1) {
            int y = __shfl_up(x, off);
            if ((int)threadIdx.x >= off) x += y;
        }
        if (i < nb) blk_sum[i] = carry + x - v;
        carry += __shfl(x, 63);
    }
}

__global__ void scan_add_kernel(int* __restrict__ row_ptr,
                                const int* __restrict__ blk_sum, int Np1) {
    int i = blockIdx.x * blockDim.x + threadIdx.x;
    if (i < Np1) row_ptr[i] += blk_sum[i >> 10];
}

// ---------------------------------------------------------------------------
// Stage 3: CSR fill (within-node order nondeterministic; fp tolerance covers)
// ---------------------------------------------------------------------------
__global__ void csr_fill_kernel(const int* __restrict__ src,
                                const int* __restrict__ dst,
                                const int* __restrict__ row_ptr,
                                int* __restrict__ cursor,
                                int* __restrict__ csr_src, int E) {
    int e = blockIdx.x * blockDim.x + threadIdx.x;
    if (e >= E) return;
    int d = dst[e];
    int pos = atomicAdd(&cursor[d], 1);
    csr_src[row_ptr[d] + pos] = src[e];
}

// ---------------------------------------------------------------------------
// W prep: split W1 into truncated-bf16 hi + bf16 residual, laid out directly
// in MFMA B-fragment order: B[k=q*8+j][n=lane&15], flat index
// (((kb*4+fb)*64 + lane)*8 + j).  K padded 500->512 with zeros (kills any
// garbage on the A side of the padded k range: 0 * x = 0).
// ---------------------------------------------------------------------------
__global__ void wprep_kernel(const float* __restrict__ W1,
                             unsigned short* __restrict__ whf,
                             unsigned short* __restrict__ wlf) {
    int idx = blockIdx.x * 256 + threadIdx.x;  // over KPAD*HDIM = 32768
    if (idx >= KPAD * HDIM) return;
    int k = idx >> 6;
    int f = idx & 63;
    float w = (k < F_IN) ? W1[k * HDIM + f] : 0.f;
    unsigned int b = __float_as_uint(w);
    unsigned short hh = (unsigned short)(b >> 16);          // trunc bf16
    float wl = w - __uint_as_float(b & 0xffff0000u);        // residual
    unsigned short ll = (unsigned short)(__float_as_uint(wl) >> 16);
    int kb = k >> 5, q = (k >> 3) & 3, j = k & 7;
    int fb = f >> 4, fl = f & 15;
    int lane = (q << 4) | fl;
    size_t o = ((((size_t)kb * 4 + fb) * 64 + lane) << 3) | (size_t)j;
    whf[o] = hh;
    wlf[o] = ll;
}

// ---------------------------------------------------------------------------
// Stage 4: h1 = x @ W1 via bf16 MFMA, 3-pass split (xh*wh + xl*wh + xh*wl).
// One wave owns 32 nodes (2 m-tiles of 16).  A-frags read straight from
// global x (fp32, split in-register); B-frags are pre-laid coalesced b128
// loads.  No LDS, no barriers.  Epilogue stores h1b = bf16(h1 * dis[n]).
// ---------------------------------------------------------------------------
__global__ __launch_bounds__(256) void gemm1_kernel(
        const float* __restrict__ x,
        const unsigned short* __restrict__ whf,
        const unsigned short* __restrict__ wlf,
        const float* __restrict__ dis,
        unsigned short* __restrict__ h1b, int N) {
    const int lane = threadIdx.x & 63;
    const int wid = (blockIdx.x * 256 + threadIdx.x) >> 6;  // global wave id
    const int n0 = wid * 32;
    if (n0 >= N) return;
    const int q = lane >> 4;
    const int fl = lane & 15;

    int r0 = n0 + fl;       if (r0 >= N) r0 = N - 1;
    int r1 = n0 + 16 + fl;  if (r1 >= N) r1 = N - 1;
    const float* xp0 = x + (size_t)r0 * F_IN + q * 8;
    const float* xp1 = x + (size_t)r1 * F_IN + q * 8;

    floatx4 acc[2][4];
#pragma unroll
    for (int t = 0; t < 2; ++t)
#pragma unroll
        for (int fb = 0; fb < 4; ++fb) acc[t][fb] = (floatx4){0.f, 0.f, 0.f, 0.f};

    const bf16x8* whv = (const bf16x8*)whf;
    const bf16x8* wlv = (const bf16x8*)wlf;

    for (int kb = 0; kb < NSTAGE; ++kb) {
        float xv0[8], xv1[8];
        if (kb < NSTAGE - 1) {
            float4 a = *(const float4*)(xp0 + kb * 32);
            float4 b = *(const float4*)(xp0 + kb * 32 + 4);
            xv0[0] = a.x; xv0[1] = a.y; xv0[2] = a.z; xv0[3] = a.w;
            xv0[4] = b.x; xv0[5] = b.y; xv0[6] = b.z; xv0[7] = b.w;
            float4 c = *(const float4*)(xp1 + kb * 32);
            float4 d = *(const float4*)(xp1 + kb * 32 + 4);
            xv1[0] = c.x; xv1[1] = c.y; xv1[2] = c.z; xv1[3] = c.w;
            xv1[4] = d.x; xv1[5] = d.y; xv1[6] = d.z; xv1[7] = d.w;
        } else {  // last stage: k 480..511, valid only k<500
#pragma unroll
            for (int j = 0; j < 8; ++j) {
                int kk = kb * 32 + q * 8 + j;
                xv0[j] = (kk < F_IN) ? xp0[kb * 32 + j] : 0.f;
                xv1[j] = (kk < F_IN) ? xp1[kb * 32 + j] : 0.f;
            }
        }
        // truncated bf16 split
        bf16x8 xh0, xl0, xh1, xl1;
#pragma unroll
        for (int j = 0; j < 8; ++j) {
            unsigned int b0 = __float_as_uint(xv0[j]);
            xh0[j] = (short)(b0 >> 16);
            float res0 = xv0[j] - __uint_as_float(b0 & 0xffff0000u);
            xl0[j] = (short)(__float_as_uint(res0) >> 16);
            unsigned int b1 = __float_as_uint(xv1[j]);
            xh1[j] = (short)(b1 >> 16);
            float res1 = xv1[j] - __uint_as_float(b1 & 0xffff0000u);
            xl1[j] = (short)(__float_as_uint(res1) >> 16);
        }
#pragma unroll
        for (int fb = 0; fb < 4; ++fb) {
            bf16x8 bh = whv[(size_t)(kb * 4 + fb) * 64 + lane];
            bf16x8 bl = wlv[(size_t)(kb * 4 + fb) * 64 + lane];
            acc[0][fb] = __builtin_amdgcn_mfma_f32_16x16x32_bf16(xh0, bh, acc[0][fb], 0, 0, 0);
            acc[0][fb] = __builtin_amdgcn_mfma_f32_16x16x32_bf16(xl0, bh, acc[0][fb], 0, 0, 0);
            acc[0][fb] = __builtin_amdgcn_mfma_f32_16x16x32_bf16(xh0, bl, acc[0][fb], 0, 0, 0);
            acc[1][fb] = __builtin_amdgcn_mfma_f32_16x16x32_bf16(xh1, bh, acc[1][fb], 0, 0, 0);
            acc[1][fb] = __builtin_amdgcn_mfma_f32_16x16x32_bf16(xl1, bh, acc[1][fb], 0, 0, 0);
            acc[1][fb] = __builtin_amdgcn_mfma_f32_16x16x32_bf16(xh1, bl, acc[1][fb], 0, 0, 0);
        }
    }
    // epilogue: D[m=q*4+r][n=lane&15]; node = n0 + t*16 + q*4 + r, feat = fb*16+fl
#pragma unroll
    for (int t = 0; t < 2; ++t) {
#pragma unroll
        for (int r = 0; r < 4; ++r) {
            int node = n0 + t * 16 + q * 4 + r;
            if (node < N) {
                float dn = dis[node];
#pragma unroll
                for (int fb = 0; fb < 4; ++fb) {
                    h1b[(size_t)node * HDIM + fb * 16 + fl] =
                        f2bf(acc[t][fb][r] * dn);
                }
            }
        }
    }
}

// ---------------------------------------------------------------------------
// Stage 5: gather layer 1.  h1b rows are pre-scaled by dis[s], so the loop is
// pure adds; multiply by dis[d] once at the end.  Wave per node, half-wave per
// edge parity, 4 edges in flight per half.
// ---------------------------------------------------------------------------
__global__ void gather1_kernel(const int* __restrict__ row_ptr,
                               const int* __restrict__ csr_src,
                               const float* __restrict__ dis,
                               const unsigned short* __restrict__ h1b,
                               float* __restrict__ agg1, int N) {
    int nid = blockIdx.x * 4 + (threadIdx.x >> 6);
    if (nid >= N) return;
    int node = __builtin_amdgcn_readfirstlane(nid);
    int lane = threadIdx.x & 63;
    int half = lane >> 5;
    int c = lane & 31;  // features 2c, 2c+1
    int beg = row_ptr[node];
    int end = row_ptr[node + 1];
    float dd = dis[node];
    float a0 = 0.f, a1 = 0.f;
    if (half == 0) {  // self-loop: row already holds h1*dis[node]
        unsigned int w = *reinterpret_cast<const unsigned int*>(
            h1b + (size_t)node * HDIM + 2 * c);
        a0 = __uint_as_float(w << 16);
        a1 = __uint_as_float(w & 0xffff0000u);
    }
    int p = beg + half;
    for (; p + 6 < end; p += 8) {  // 4 edges in flight per half
        int s0 = csr_src[p];
        int s1 = csr_src[p + 2];
        int s2 = csr_src[p + 4];
        int s3 = csr_src[p + 6];
        unsigned int w0 = *reinterpret_cast<const unsigned int*>(h1b + (size_t)s0 * HDIM + 2 * c);
        unsigned int w1 = *reinterpret_cast<const unsigned int*>(h1b + (size_t)s1 * HDIM + 2 * c);
        unsigned int w2 = *reinterpret_cast<const unsigned int*>(h1b + (size_t)s2 * HDIM + 2 * c);
        unsigned int w3 = *reinterpret_cast<const unsigned int*>(h1b + (size_t)s3 * HDIM + 2 * c);
        a0 += __uint_as_float(w0 << 16);
        a1 += __uint_as_float(w0 & 0xffff0000u);
        a0 += __uint_as_float(w1 << 16);
        a1 += __uint_as_float(w1 & 0xffff0000u);
        a0 += __uint_as_float(w2 << 16);
        a1 += __uint_as_float(w2 & 0xffff0000u);
        a0 += __uint_as_float(w3 << 16);
        a1 += __uint_as_float(w3 & 0xffff0000u);
    }
    for (; p < end; p += 2) {
        int s0 = csr_src[p];
        unsigned int w0 = *reinterpret_cast<const unsigned int*>(h1b + (size_t)s0 * HDIM + 2 * c);
        a0 += __uint_as_float(w0 << 16);
        a1 += __uint_as_float(w0 & 0xffff0000u);
    }
    a0 += __shfl_xor(a0, 32);
    a1 += __shfl_xor(a1, 32);
    if (half == 0) {
        *reinterpret_cast<float2*>(agg1 + (size_t)node * HDIM + 2 * c) =
            make_float2(a0 * dd, a1 * dd);
    }
}

// ---------------------------------------------------------------------------
// Stage 6: layer 2 dense: t = relu(agg1+b1); h2s = (t @ W2) * dis[n]
// ---------------------------------------------------------------------------
__global__ void layer2_kernel(const float* __restrict__ agg1,
                              const float* __restrict__ b1,
                              const float* __restrict__ W2,
                              const float* __restrict__ dis,
                              float* __restrict__ h2s, int N) {
    int n = blockIdx.x * blockDim.x + threadIdx.x;
    if (n >= N) return;
    const float* ar = agg1 + (size_t)n * HDIM;
    float t[HDIM];
#pragma unroll
    for (int c = 0; c < HDIM; ++c) {
        float v = ar[c] + b1[c];
        t[c] = v > 0.f ? v : 0.f;
    }
    float dn = dis[n];
    float* h2r = h2s + (size_t)n * CDIM;
#pragma unroll
    for (int j = 0; j < CDIM; ++j) {
        float acc = 0.f;
#pragma unroll
        for (int c = 0; c < HDIM; ++c) acc = fmaf(t[c], W2[c * CDIM + j], acc);
        h2r[j] = acc * dn;
    }
}

// ---------------------------------------------------------------------------
// Stage 7: gather layer 2.  Wave per node, 4 edge-groups x 16 lanes, shfl
// reduce.  h2s pre-scaled by dis[s].
// ---------------------------------------------------------------------------
__global__ void gather2_kernel(const int* __restrict__ row_ptr,
                               const int* __restrict__ csr_src,
                               const float* __restrict__ dis,
                               const float* __restrict__ h2s,
                               const float* __restrict__ b2,
                               float* __restrict__ out, int N) {
    int nid = blockIdx.x * 4 + (threadIdx.x >> 6);
    if (nid >= N) return;
    int node = __builtin_amdgcn_readfirstlane(nid);
    int lane = threadIdx.x & 63;
    int g = lane >> 4;
    int j = lane & 15;
    int jj = (j < CDIM) ? j : CDIM - 1;  // clamp loads (garbage stays in j>=10 lanes)
    int beg = row_ptr[node];
    int end = row_ptr[node + 1];
    float acc = 0.f;
    for (int p = beg + g; p < end; p += 4) {
        int s = csr_src[p];
        acc += h2s[(size_t)s * CDIM + jj];
    }
    acc += __shfl_xor(acc, 16);
    acc += __shfl_xor(acc, 32);
    if (lane < CDIM) {
        float dd = dis[node];
        out[(size_t)node * CDIM + lane] =
            b2[lane] + dd * (acc + h2s[(size_t)node * CDIM + lane]);
    }
}

// ---------------------------------------------------------------------------
static inline char* align256(char* p) {
    return (char*)(((uintptr_t)p + 255) & ~(uintptr_t)255);
}

extern "C" void kernel_launch(void* const* d_in, const int* in_sizes, int n_in,
                              void* d_out, int out_size, void* d_ws,
                              size_t ws_size, hipStream_t stream) {
    const float* x  = (const float*)d_in[0];
    const int*   ei = (const int*)d_in[1];
    const float* W1 = (const float*)d_in[2];
    const float* b1 = (const float*)d_in[3];
    const float* W2 = (const float*)d_in[4];
    const float* b2 = (const float*)d_in[5];

    const int N = in_sizes[0] / F_IN;   // 100000
    const int E = in_sizes[1] / 2;      // 1600000
    const int* src = ei;
    const int* dst = ei + E;
    float* out = (float*)d_out;

    const int Np1 = N + 1;
    const int nscan_blocks = (Np1 + 1023) / 1024;

    // workspace layout (~47 MB), 256B-aligned chunks
    char* w = (char*)d_ws;
    int* deg = (int*)w;                  w = align256(w + (size_t)N * 4);      // zeroed
    int* cursor = (int*)w;               w = align256(w + (size_t)N * 4);      // zeroed
    float* dis = (float*)w;              w = align256(w + (size_t)N * 4);
    int* row_ptr = (int*)w;              w = align256(w + (size_t)(N + 4) * 4);
    int* blk_sum = (int*)w;              w = align256(w + (size_t)nscan_blocks * 4);
    int* csr_src = (int*)w;              w = align256(w + (size_t)E * 4);
    unsigned short* whf = (unsigned short*)w;  w = align256(w + (size_t)KPAD * HDIM * 2);
    unsigned short* wlf = (unsigned short*)w;  w = align256(w + (size_t)KPAD * HDIM * 2);
    unsigned short* h1b = (unsigned short*)w;  w = align256(w + (size_t)N * HDIM * 2);
    float* agg1 = (float*)w;             w = align256(w + (size_t)N * HDIM * 4);
    float* h2s = (float*)h1b;            // h1b dead after gather1; reuse (4 < 12.8 MB)

    hipMemsetAsync(deg, 0, (size_t)N * 2 * 4, stream);  // deg + cursor (contiguous-ish)
    hipMemsetAsync(cursor, 0, (size_t)N * 4, stream);   // cursor (aligned copy is separate)

    wprep_kernel<<<(KPAD * HDIM + 255) / 256, 256, 0, stream>>>(W1, whf, wlf);
    deg_count_kernel<<<(E + 255) / 256, 256, 0, stream>>>(dst, E, deg);
    scan_block_kernel<<<nscan_blocks, 1024, 0, stream>>>(deg, row_ptr, blk_sum,
                                                         dis, Np1);
    scan_top_kernel<<<1, 64, 0, stream>>>(blk_sum, nscan_blocks);
    scan_add_kernel<<<(Np1 + 255) / 256, 256, 0, stream>>>(row_ptr, blk_sum,
                                                           Np1);
    csr_fill_kernel<<<(E + 255) / 256, 256, 0, stream>>>(src, dst, row_ptr,
                                                         cursor, csr_src, E);
    {
        int nwaves = (N + 31) / 32;
        int blocks = (nwaves + 3) / 4;
        gemm1_kernel<<<blocks, 256, 0, stream>>>(x, whf, wlf, dis, h1b, N);
    }
    gather1_kernel<<<(N + 3) / 4, 256, 0, stream>>>(row_ptr, csr_src, dis, h1b,
                                                    agg1, N);
    layer2_kernel<<<(N + 255) / 256, 256, 0, stream>>>(agg1, b1, W2, dis, h2s,
                                                       N);
    gather2_kernel<<<(N + 3) / 4, 256, 0, stream>>>(row_ptr, csr_src, dis, h2s,
                                                    b2, out, N);
}